// Round 1
// baseline (832.260 us; speedup 1.0000x reference)
//
#include <hip/hip_runtime.h>
#include <math.h>

#define BN 4
#define HIq 128
#define WIq 128
#define DIM 128
#define HOq 64
#define WOq 64
#define NPOS 4096      // HO*WO
#define NTOK 16384     // HI*WI
#define EPS_LN 1e-5f
#define EPS_A 1e-6f

__device__ __forceinline__ int nb_index(int h, int w, int t) {
    int ch = min(max(h, 1), HOq - 2);
    int cw = min(max(w, 1), WOq - 2);
    int dr = t / 3 - 1, dc = t % 3 - 1;
    return (ch + dr) * WOq + (cw + dc);
}

// ---------------------------------------------------------------------------
// conv_w [O][I][3][3] -> cwt [tap][I][O]  (coalesced-in-o reads later)
__global__ void conv_w_transpose(const float* __restrict__ cw, float* __restrict__ cwt) {
    int i   = blockIdx.x;   // I
    int tap = blockIdx.y;   // kh*3+kw
    int o   = threadIdx.x;  // O
    cwt[(tap * DIM + i) * DIM + o] = cw[(o * DIM + i) * 9 + tap];
}

// ---------------------------------------------------------------------------
// LN(x)@k_w and x@v_w, scattered into grouped layout [b][g][ho][wo][d].
// 8 tokens / block of 256.
__global__ void kv_proj_kernel(const float* __restrict__ x,
                               const float* __restrict__ k_w,
                               const float* __restrict__ v_w,
                               const float* __restrict__ ln_g,
                               const float* __restrict__ ln_b,
                               float* __restrict__ k_g,
                               float* __restrict__ v_g) {
    __shared__ float sx[8][DIM];
    __shared__ float sxln[8][DIM];
    int tid = threadIdx.x;
    long tokBase = (long)blockIdx.x * 8;

    #pragma unroll
    for (int kk = 0; kk < 4; ++kk) {
        int idx = kk * 256 + tid;             // 0..1023
        int r = idx >> 7, d = idx & 127;
        sx[r][d] = x[(tokBase + r) * DIM + d];
    }
    __syncthreads();

    int wv = tid >> 6, lane = tid & 63;
    #pragma unroll
    for (int rr = 0; rr < 2; ++rr) {
        int r = wv * 2 + rr;
        float v0 = sx[r][lane], v1 = sx[r][lane + 64];
        float s = v0 + v1, ss = v0 * v0 + v1 * v1;
        #pragma unroll
        for (int off = 32; off; off >>= 1) {
            s  += __shfl_xor(s, off, 64);
            ss += __shfl_xor(ss, off, 64);
        }
        float mu = s * (1.0f / DIM);
        float var = fmaxf(ss * (1.0f / DIM) - mu * mu, 0.0f);
        float rstd = rsqrtf(var + EPS_LN);
        sxln[r][lane]      = (v0 - mu) * rstd * ln_g[lane]      + ln_b[lane];
        sxln[r][lane + 64] = (v1 - mu) * rstd * ln_g[lane + 64] + ln_b[lane + 64];
    }
    __syncthreads();

    int d = tid & 127, half = tid >> 7;   // half: tokens half*4 .. half*4+3
    float acck[4] = {0.f, 0.f, 0.f, 0.f};
    float accv[4] = {0.f, 0.f, 0.f, 0.f};
    for (int i = 0; i < DIM; ++i) {
        float wk = k_w[i * DIM + d];
        float wvv = v_w[i * DIM + d];
        #pragma unroll
        for (int r = 0; r < 4; ++r) {
            acck[r] += sxln[half * 4 + r][i] * wk;
            accv[r] += sx[half * 4 + r][i] * wvv;
        }
    }
    #pragma unroll
    for (int r = 0; r < 4; ++r) {
        long tok = tokBase + half * 4 + r;
        int b = (int)(tok >> 14);
        int pix = (int)(tok & 16383);
        int ih = pix >> 7, iw = pix & 127;
        int ho = ih >> 1, p = ih & 1, wo = iw >> 1, qq = iw & 1;
        int g = p * 2 + qq;
        long out = ((long)(b * 4 + g) * NPOS + (ho * WOq + wo)) * DIM + d;
        k_g[out] = acck[r];
        v_g[out] = accv[r];
    }
}

// ---------------------------------------------------------------------------
// 3x3 stride-2 pad-1 conv, NCHW-as-(B,pix,ch). 8 output pixels per block.
__global__ void conv_kernel(const float* __restrict__ x,
                            const float* __restrict__ cwt,
                            float* __restrict__ seed) {
    __shared__ float sin_[3][18][DIM];
    int tid = threadIdx.x;              // o
    int wc = blockIdx.x;                // 0..7
    int ho = blockIdx.y;
    int b  = blockIdx.z;

    for (int idx = 0; idx < 54; ++idx) {
        int r = idx / 18, c = idx % 18;
        int hi = 2 * ho - 1 + r;
        int wi = 16 * wc - 1 + c;
        float v = 0.0f;
        if (hi >= 0 && hi < HIq && wi >= 0 && wi < WIq)
            v = x[((long)b * NTOK + hi * WIq + wi) * DIM + tid];
        sin_[r][c][tid] = v;
    }
    __syncthreads();

    float acc[8] = {0.f, 0.f, 0.f, 0.f, 0.f, 0.f, 0.f, 0.f};
    for (int tap = 0; tap < 9; ++tap) {
        int kh = tap / 3, kw = tap % 3;
        for (int i = 0; i < DIM; ++i) {
            float wgt = cwt[(tap * DIM + i) * DIM + tid];
            #pragma unroll
            for (int ws = 0; ws < 8; ++ws) {
                acc[ws] += sin_[kh][2 * ws + kw][i] * wgt;
            }
        }
    }
    #pragma unroll
    for (int ws = 0; ws < 8; ++ws) {
        int wo = wc * 8 + ws;
        seed[((long)b * NPOS + ho * WOq + wo) * DIM + tid] = acc[ws];
    }
}

// ---------------------------------------------------------------------------
// row-wise LN (128 threads per row, 2 waves)
__global__ void ln_kernel(const float* __restrict__ in, float* __restrict__ out,
                          const float* __restrict__ g, const float* __restrict__ bb) {
    int row = blockIdx.x, tid = threadIdx.x;
    float v = in[(long)row * DIM + tid];
    float s = v, ss = v * v;
    int lane = tid & 63, wv = tid >> 6;
    #pragma unroll
    for (int off = 32; off; off >>= 1) {
        s  += __shfl_xor(s, off, 64);
        ss += __shfl_xor(ss, off, 64);
    }
    __shared__ float red[4];
    if (lane == 0) { red[wv] = s; red[2 + wv] = ss; }
    __syncthreads();
    float S = red[0] + red[1], SS = red[2] + red[3];
    float mu = S * (1.0f / DIM);
    float var = fmaxf(SS * (1.0f / DIM) - mu * mu, 0.0f);
    float rstd = rsqrtf(var + EPS_LN);
    out[(long)row * DIM + tid] = (v - mu) * rstd * g[tid] + bb[tid];
}

// ---------------------------------------------------------------------------
// q = LN(x_out)@q_w ; 8 tokens / block of 256
__global__ void q_proj_kernel(const float* __restrict__ x_out,
                              const float* __restrict__ q_w,
                              const float* __restrict__ ln_g,
                              const float* __restrict__ ln_b,
                              float* __restrict__ q) {
    __shared__ float sx[8][DIM];
    __shared__ float sxln[8][DIM];
    int tid = threadIdx.x;
    long base = (long)blockIdx.x * 8;

    #pragma unroll
    for (int kk = 0; kk < 4; ++kk) {
        int idx = kk * 256 + tid;
        int r = idx >> 7, d = idx & 127;
        sx[r][d] = x_out[(base + r) * DIM + d];
    }
    __syncthreads();

    int wv = tid >> 6, lane = tid & 63;
    #pragma unroll
    for (int rr = 0; rr < 2; ++rr) {
        int r = wv * 2 + rr;
        float v0 = sx[r][lane], v1 = sx[r][lane + 64];
        float s = v0 + v1, ss = v0 * v0 + v1 * v1;
        #pragma unroll
        for (int off = 32; off; off >>= 1) {
            s  += __shfl_xor(s, off, 64);
            ss += __shfl_xor(ss, off, 64);
        }
        float mu = s * (1.0f / DIM);
        float var = fmaxf(ss * (1.0f / DIM) - mu * mu, 0.0f);
        float rstd = rsqrtf(var + EPS_LN);
        sxln[r][lane]      = (v0 - mu) * rstd * ln_g[lane]      + ln_b[lane];
        sxln[r][lane + 64] = (v1 - mu) * rstd * ln_g[lane + 64] + ln_b[lane + 64];
    }
    __syncthreads();

    int d = tid & 127, half = tid >> 7;
    float acc[4] = {0.f, 0.f, 0.f, 0.f};
    for (int i = 0; i < DIM; ++i) {
        float w = q_w[i * DIM + d];
        #pragma unroll
        for (int r = 0; r < 4; ++r) acc[r] += sxln[half * 4 + r][i] * w;
    }
    #pragma unroll
    for (int r = 0; r < 4; ++r)
        q[(base + half * 4 + r) * DIM + d] = acc[r];
}

// ---------------------------------------------------------------------------
__global__ void zero_kernel(float* __restrict__ p, int n) {
    int i = blockIdx.x * blockDim.x + threadIdx.x;
    if (i < n) p[i] = 0.0f;
}

// ---------------------------------------------------------------------------
// attn: one wave per (b,g,h,w) cell; 9 dots of length 128, softmax, +eps,
// write attn to d_out and atomically accumulate col_sums.
__global__ void attn_kernel(const float* __restrict__ k_g,
                            const float* __restrict__ q,
                            const float* __restrict__ rpb,
                            const float* __restrict__ tau,
                            float* __restrict__ attn_out,
                            float* __restrict__ col_sums) {
    int tid = threadIdx.x;
    int wv = tid >> 6, lane = tid & 63;
    int cell = blockIdx.x * 4 + wv;     // ((b*4+g)*4096 + pos)
    int b = cell >> 14;
    int rem = cell & 16383;
    int g = rem >> 12;
    int pos = rem & 4095;
    int h = pos >> 6, w = pos & 63;

    const float2* kp = (const float2*)(k_g + (long)cell * DIM);
    float2 kv2 = kp[lane];
    float scale = expf(tau[0]);

    float l[9];
    #pragma unroll
    for (int t = 0; t < 9; ++t) {
        int n = nb_index(h, w, t);
        const float2* qp = (const float2*)(q + ((long)b * NPOS + n) * DIM);
        float2 qv = qp[lane];
        float p = kv2.x * qv.x + kv2.y * qv.y;
        #pragma unroll
        for (int off = 32; off; off >>= 1) p += __shfl_xor(p, off, 64);
        l[t] = (p + rpb[g * 9 + t]) * scale;
    }
    float m = l[0];
    #pragma unroll
    for (int t = 1; t < 9; ++t) m = fmaxf(m, l[t]);
    float e[9], s = 0.f;
    #pragma unroll
    for (int t = 0; t < 9; ++t) { e[t] = __expf(l[t] - m); s += e[t]; }
    float inv = 1.0f / s;

    float myv = 0.f; int myn = 0;
    #pragma unroll
    for (int t = 0; t < 9; ++t) {
        float a = e[t] * inv + EPS_A;
        if (lane == t) { myv = a; myn = nb_index(h, w, t); }
    }
    if (lane < 9) {
        attn_out[(long)cell * 9 + lane] = myv;
        atomicAdd(&col_sums[b * NPOS + myn], myv);
    }
}

// ---------------------------------------------------------------------------
// A_col = attn / (colsum gather + 1e-8); upd = sum_{g,t} A_col * v_nb;
// x_out += upd. One block of 128 per (b,pos).
__global__ void acol_upd_kernel(const float* __restrict__ attn_out,
                                const float* __restrict__ col_sums,
                                const float* __restrict__ v_g,
                                float* __restrict__ acol_out,
                                float* __restrict__ x_out) {
    __shared__ float sA[36];
    int tid = threadIdx.x;
    int row = blockIdx.x;               // b*NPOS+pos
    int b = row >> 12, pos = row & 4095;
    int h = pos >> 6, w = pos & 63;

    if (tid < 36) {
        int g = tid / 9, t = tid % 9;
        long ci = ((long)(b * 4 + g) * NPOS + pos) * 9 + t;
        float a = attn_out[ci];
        float cs = col_sums[b * NPOS + nb_index(h, w, t)];
        float A = a / (cs + 1e-8f);
        sA[tid] = A;
        acol_out[ci] = A;
    }
    __syncthreads();

    int nn[9];
    #pragma unroll
    for (int t = 0; t < 9; ++t) nn[t] = nb_index(h, w, t);

    float acc = 0.f;
    #pragma unroll
    for (int g = 0; g < 4; ++g) {
        const float* vb = v_g + (long)(b * 4 + g) * NPOS * DIM;
        #pragma unroll
        for (int t = 0; t < 9; ++t) {
            acc += sA[g * 9 + t] * vb[(long)nn[t] * DIM + tid];
        }
    }
    x_out[(long)row * DIM + tid] += acc;
}

// ---------------------------------------------------------------------------
// MLP: h=gelu(x@w1+b1); o=h@w2+b2; x += LN(o). 4 tokens / block of 256.
__global__ void mlp_kernel(float* __restrict__ x_out,
                           const float* __restrict__ w1, const float* __restrict__ b1,
                           const float* __restrict__ w2, const float* __restrict__ b2,
                           const float* __restrict__ ln_g, const float* __restrict__ ln_b) {
    __shared__ float sx[4][DIM];
    __shared__ float sh[4][2 * DIM];
    __shared__ float sm[4][DIM];
    int tid = threadIdx.x;
    long base = (long)blockIdx.x * 4;

    #pragma unroll
    for (int kk = 0; kk < 2; ++kk) {
        int idx = kk * 256 + tid;       // 0..511
        int r = idx >> 7, d = idx & 127;
        sx[r][d] = x_out[(base + r) * DIM + d];
    }
    __syncthreads();

    // hidden (256-wide): thread j
    int j = tid;
    float bj = b1[j];
    float acc[4] = {bj, bj, bj, bj};
    for (int i = 0; i < DIM; ++i) {
        float w = w1[i * 2 * DIM + j];
        #pragma unroll
        for (int r = 0; r < 4; ++r) acc[r] += sx[r][i] * w;
    }
    #pragma unroll
    for (int r = 0; r < 4; ++r) {
        float hv = acc[r];
        hv = 0.5f * hv * (1.0f + erff(hv * 0.70710678118654752f));
        sh[r][j] = hv;
    }
    __syncthreads();

    // out (128-wide): thread (half,d) handles tokens half*2, half*2+1
    int d = tid & 127, half = tid >> 7;
    float o0 = b2[d], o1 = b2[d];
    for (int jj = 0; jj < 2 * DIM; ++jj) {
        float w = w2[jj * DIM + d];
        o0 += sh[half * 2 + 0][jj] * w;
        o1 += sh[half * 2 + 1][jj] * w;
    }
    sm[half * 2 + 0][d] = o0;
    sm[half * 2 + 1][d] = o1;
    __syncthreads();

    // LN + residual: wave wv handles token wv
    int wv = tid >> 6, lane = tid & 63;
    float v0 = sm[wv][lane], v1 = sm[wv][lane + 64];
    float s = v0 + v1, ss = v0 * v0 + v1 * v1;
    #pragma unroll
    for (int off = 32; off; off >>= 1) {
        s  += __shfl_xor(s, off, 64);
        ss += __shfl_xor(ss, off, 64);
    }
    float mu = s * (1.0f / DIM);
    float var = fmaxf(ss * (1.0f / DIM) - mu * mu, 0.0f);
    float rstd = rsqrtf(var + EPS_LN);
    x_out[(base + wv) * DIM + lane] =
        sx[wv][lane] + (v0 - mu) * rstd * ln_g[lane] + ln_b[lane];
    x_out[(base + wv) * DIM + lane + 64] =
        sx[wv][lane + 64] + (v1 - mu) * rstd * ln_g[lane + 64] + ln_b[lane + 64];
}

// ---------------------------------------------------------------------------
extern "C" void kernel_launch(void* const* d_in, const int* in_sizes, int n_in,
                              void* d_out, int out_size, void* d_ws, size_t ws_size,
                              hipStream_t stream) {
    const float* x        = (const float*)d_in[0];
    const float* conv_w   = (const float*)d_in[1];
    const float* q_w      = (const float*)d_in[2];
    const float* k_w      = (const float*)d_in[3];
    const float* v_w      = (const float*)d_in[4];
    const float* mlp_w1   = (const float*)d_in[5];
    const float* mlp_b1   = (const float*)d_in[6];
    const float* mlp_w2   = (const float*)d_in[7];
    const float* mlp_b2   = (const float*)d_in[8];
    const float* ln_in_g  = (const float*)d_in[9];
    const float* ln_in_b  = (const float*)d_in[10];
    const float* ln_out_g = (const float*)d_in[11];
    const float* ln_out_b = (const float*)d_in[12];
    const float* tau      = (const float*)d_in[13];
    const float* rpb      = (const float*)d_in[14];

    float* out_x    = (float*)d_out;                        // [4][4096][128]
    float* out_attn = out_x + (long)BN * NPOS * DIM;        // [4][4][64][64][9]
    float* out_acol = out_attn + (long)BN * 4 * NPOS * 9;   // [4][4][64][64][9]

    float* ws = (float*)d_ws;
    float* k_g      = ws; ws += (long)BN * 4 * NPOS * DIM;  // 8.39M
    float* v_g      = ws; ws += (long)BN * 4 * NPOS * DIM;  // 8.39M
    float* seed     = ws; ws += (long)BN * NPOS * DIM;      // 2.10M
    float* qbuf     = ws; ws += (long)BN * NPOS * DIM;      // 2.10M
    float* cwt      = ws; ws += 9 * DIM * DIM;              // 147K
    float* col_sums = ws; ws += BN * NPOS;                  // 16K

    conv_w_transpose<<<dim3(DIM, 9), 128, 0, stream>>>(conv_w, cwt);
    kv_proj_kernel<<<8192, 256, 0, stream>>>(x, k_w, v_w, ln_in_g, ln_in_b, k_g, v_g);
    conv_kernel<<<dim3(8, HOq, BN), 128, 0, stream>>>(x, cwt, seed);
    ln_kernel<<<BN * NPOS, 128, 0, stream>>>(seed, out_x, ln_out_g, ln_out_b);

    for (int it = 0; it < 3; ++it) {
        q_proj_kernel<<<2048, 256, 0, stream>>>(out_x, q_w, ln_out_g, ln_out_b, qbuf);
        zero_kernel<<<(BN * NPOS + 255) / 256, 256, 0, stream>>>(col_sums, BN * NPOS);
        attn_kernel<<<16384, 256, 0, stream>>>(k_g, qbuf, rpb, tau, out_attn, col_sums);
        acol_upd_kernel<<<16384, 128, 0, stream>>>(out_attn, col_sums, v_g, out_acol, out_x);
        mlp_kernel<<<4096, 256, 0, stream>>>(out_x, mlp_w1, mlp_b1, mlp_w2, mlp_b2,
                                             ln_out_g, ln_out_b);
    }
}

// Round 2
// 573.188 us; speedup vs baseline: 1.4520x; 1.4520x over previous
//
#include <hip/hip_runtime.h>
#include <hip/hip_bf16.h>
#include <math.h>

#define BN 4
#define HIq 128
#define WIq 128
#define DIM 128
#define HOq 64
#define WOq 64
#define NPOS 4096      // HO*WO
#define NTOK 16384     // HI*WI
#define EPS_LN 1e-5f
#define EPS_A 1e-6f

typedef __attribute__((ext_vector_type(8))) short bf16x8;
typedef __attribute__((ext_vector_type(4))) float f32x4;

__device__ __forceinline__ unsigned short f2bf(float f) {
    unsigned int u = __float_as_uint(f);
    u = (u + 0x7FFFu + ((u >> 16) & 1u)) >> 16;
    return (unsigned short)u;
}

__device__ __forceinline__ int nb_index(int h, int w, int t) {
    int ch = min(max(h, 1), HOq - 2);
    int cw = min(max(w, 1), WOq - 2);
    int dr = t / 3 - 1, dc = t % 3 - 1;
    return (ch + dr) * WOq + (cw + dc);
}

// ---------------------------------------------------------------------------
// x -> bf16, LN(x) -> bf16. Wave wv handles row blockIdx*4+wv.
__global__ void prep_ln_kernel(const float* __restrict__ x,
                               const float* __restrict__ g,
                               const float* __restrict__ bb,
                               unsigned short* __restrict__ x_bf,
                               unsigned short* __restrict__ xln_bf) {
    int tid = threadIdx.x, wv = tid >> 6, lane = tid & 63;
    long row = (long)blockIdx.x * 4 + wv;
    const float* xr = x + row * DIM;
    float v0 = xr[lane], v1 = xr[lane + 64];
    float s = v0 + v1, ss = v0 * v0 + v1 * v1;
    #pragma unroll
    for (int off = 32; off; off >>= 1) {
        s  += __shfl_xor(s, off, 64);
        ss += __shfl_xor(ss, off, 64);
    }
    float mu = s * (1.0f / DIM);
    float var = fmaxf(ss * (1.0f / DIM) - mu * mu, 0.0f);
    float rstd = rsqrtf(var + EPS_LN);
    x_bf[row * DIM + lane]        = f2bf(v0);
    x_bf[row * DIM + lane + 64]   = f2bf(v1);
    xln_bf[row * DIM + lane]      = f2bf((v0 - mu) * rstd * g[lane] + bb[lane]);
    xln_bf[row * DIM + lane + 64] = f2bf((v1 - mu) * rstd * g[lane + 64] + bb[lane + 64]);
}

// ---------------------------------------------------------------------------
// conv_w [O][I][3][3] -> wt [o][tap*128+i] bf16 (row-major-K "B^T" operand)
__global__ void conv_wt_kernel(const float* __restrict__ cw, unsigned short* __restrict__ wt) {
    int o = blockIdx.x, tap = blockIdx.y, i = threadIdx.x;
    wt[(long)o * 1152 + tap * 128 + i] = f2bf(cw[((long)o * 128 + i) * 9 + tap]);
}

// k_w/v_w [i][o] -> [o][i] bf16
__global__ void kv_wt_kernel(const float* __restrict__ kw, const float* __restrict__ vw,
                             unsigned short* __restrict__ kwt, unsigned short* __restrict__ vwt) {
    int o = blockIdx.x, i = threadIdx.x;
    kwt[o * DIM + i] = f2bf(kw[i * DIM + o]);
    vwt[o * DIM + i] = f2bf(vw[i * DIM + o]);
}

// ---------------------------------------------------------------------------
// Conv as implicit-im2col MFMA GEMM. Block = one (b,ho) strip:
// M=64 output pixels (wo), N=128 out channels, K=1152 (tap-major, i-minor).
// 4 waves in 2x2: wave (wr,wc) computes rows wr*32..+32, cols wc*64..+64.
__global__ __launch_bounds__(256) void conv_mfma_kernel(
        const unsigned short* __restrict__ x_bf,
        const unsigned short* __restrict__ wt,
        float* __restrict__ seed) {
    __shared__ unsigned short As[64][40];    // [m=wo][k(32)+pad]
    __shared__ unsigned short Bs[128][40];   // [n=o][k(32)+pad]
    int tid = threadIdx.x;
    int wv = tid >> 6, lane = tid & 63;
    int quad = lane >> 4, l15 = lane & 15;
    int wr = wv >> 1, wc = wv & 1;
    int b = blockIdx.x >> 6, ho = blockIdx.x & 63;

    f32x4 acc[2][4];
    #pragma unroll
    for (int mt = 0; mt < 2; ++mt)
        #pragma unroll
        for (int nt = 0; nt < 4; ++nt) acc[mt][nt] = (f32x4){0.f, 0.f, 0.f, 0.f};

    int m = tid >> 2, seg = tid & 3;
    for (int tap = 0; tap < 9; ++tap) {
        int kh = tap / 3, kw = tap % 3;
        int hi = 2 * ho - 1 + kh;
        int wi = 2 * m - 1 + kw;
        bool ok = (hi >= 0) && (hi < HIq) && (wi >= 0) && (wi < WIq);
        long arow = (((long)b * HIq + hi) * WIq + wi) * DIM;
        #pragma unroll
        for (int ib = 0; ib < 4; ++ib) {
            __syncthreads();
            int4 av = {0, 0, 0, 0};
            if (ok) av = *(const int4*)(x_bf + arow + ib * 32 + seg * 8);
            *(int4*)&As[m][seg * 8] = av;
            #pragma unroll
            for (int r2 = 0; r2 < 2; ++r2) {
                int lin = r2 * 256 + tid;
                int n = lin >> 2, sg = lin & 3;
                *(int4*)&Bs[n][sg * 8] =
                    *(const int4*)(wt + (long)n * 1152 + tap * 128 + ib * 32 + sg * 8);
            }
            __syncthreads();
            bf16x8 afr[2], bfr[4];
            #pragma unroll
            for (int mt = 0; mt < 2; ++mt)
                afr[mt] = *(bf16x8*)&As[wr * 32 + mt * 16 + l15][quad * 8];
            #pragma unroll
            for (int nt = 0; nt < 4; ++nt)
                bfr[nt] = *(bf16x8*)&Bs[wc * 64 + nt * 16 + l15][quad * 8];
            #pragma unroll
            for (int mt = 0; mt < 2; ++mt)
                #pragma unroll
                for (int nt = 0; nt < 4; ++nt)
                    acc[mt][nt] = __builtin_amdgcn_mfma_f32_16x16x32_bf16(
                        afr[mt], bfr[nt], acc[mt][nt], 0, 0, 0);
        }
    }
    long outb = ((long)b * NPOS + ho * WOq) * DIM;
    #pragma unroll
    for (int mt = 0; mt < 2; ++mt)
        #pragma unroll
        for (int r = 0; r < 4; ++r) {
            int wo = wr * 32 + mt * 16 + quad * 4 + r;
            #pragma unroll
            for (int nt = 0; nt < 4; ++nt) {
                int col = wc * 64 + nt * 16 + l15;
                seed[outb + (long)wo * DIM + col] = acc[mt][nt][r];
            }
        }
}

// ---------------------------------------------------------------------------
// k = LN(x)@k_w and v = x@v_w as dual MFMA GEMM, scattered to grouped layout.
// Block: M=64 tokens, N=128, K=128.
__global__ __launch_bounds__(256) void kv_mfma_kernel(
        const unsigned short* __restrict__ x_bf,
        const unsigned short* __restrict__ xln_bf,
        const unsigned short* __restrict__ kwt,
        const unsigned short* __restrict__ vwt,
        float* __restrict__ k_g, float* __restrict__ v_g) {
    __shared__ unsigned short Ak[64][40], Av[64][40];
    __shared__ unsigned short Bk[128][40], Bv[128][40];
    int tid = threadIdx.x;
    int wv = tid >> 6, lane = tid & 63;
    int quad = lane >> 4, l15 = lane & 15;
    int wr = wv >> 1, wc = wv & 1;
    long tokBase = (long)blockIdx.x * 64;

    f32x4 acck[2][4], accv[2][4];
    #pragma unroll
    for (int mt = 0; mt < 2; ++mt)
        #pragma unroll
        for (int nt = 0; nt < 4; ++nt) {
            acck[mt][nt] = (f32x4){0.f, 0.f, 0.f, 0.f};
            accv[mt][nt] = (f32x4){0.f, 0.f, 0.f, 0.f};
        }

    int m = tid >> 2, seg = tid & 3;
    #pragma unroll
    for (int ib = 0; ib < 4; ++ib) {
        __syncthreads();
        *(int4*)&Ak[m][seg * 8] = *(const int4*)(xln_bf + (tokBase + m) * DIM + ib * 32 + seg * 8);
        *(int4*)&Av[m][seg * 8] = *(const int4*)(x_bf   + (tokBase + m) * DIM + ib * 32 + seg * 8);
        #pragma unroll
        for (int r2 = 0; r2 < 2; ++r2) {
            int lin = r2 * 256 + tid;
            int n = lin >> 2, sg = lin & 3;
            *(int4*)&Bk[n][sg * 8] = *(const int4*)(kwt + (long)n * DIM + ib * 32 + sg * 8);
            *(int4*)&Bv[n][sg * 8] = *(const int4*)(vwt + (long)n * DIM + ib * 32 + sg * 8);
        }
        __syncthreads();
        bf16x8 ak[2], av2[2], bk[4], bv[4];
        #pragma unroll
        for (int mt = 0; mt < 2; ++mt) {
            ak[mt]  = *(bf16x8*)&Ak[wr * 32 + mt * 16 + l15][quad * 8];
            av2[mt] = *(bf16x8*)&Av[wr * 32 + mt * 16 + l15][quad * 8];
        }
        #pragma unroll
        for (int nt = 0; nt < 4; ++nt) {
            bk[nt] = *(bf16x8*)&Bk[wc * 64 + nt * 16 + l15][quad * 8];
            bv[nt] = *(bf16x8*)&Bv[wc * 64 + nt * 16 + l15][quad * 8];
        }
        #pragma unroll
        for (int mt = 0; mt < 2; ++mt)
            #pragma unroll
            for (int nt = 0; nt < 4; ++nt) {
                acck[mt][nt] = __builtin_amdgcn_mfma_f32_16x16x32_bf16(ak[mt],  bk[nt], acck[mt][nt], 0, 0, 0);
                accv[mt][nt] = __builtin_amdgcn_mfma_f32_16x16x32_bf16(av2[mt], bv[nt], accv[mt][nt], 0, 0, 0);
            }
    }
    #pragma unroll
    for (int mt = 0; mt < 2; ++mt)
        #pragma unroll
        for (int r = 0; r < 4; ++r) {
            long tok = tokBase + wr * 32 + mt * 16 + quad * 4 + r;
            int b = (int)(tok >> 14);
            int pix = (int)(tok & 16383);
            int ih = pix >> 7, iw = pix & 127;
            int g = (ih & 1) * 2 + (iw & 1);
            int pos = (ih >> 1) * WOq + (iw >> 1);
            long base = ((long)(b * 4 + g) * NPOS + pos) * DIM;
            #pragma unroll
            for (int nt = 0; nt < 4; ++nt) {
                int col = wc * 64 + nt * 16 + l15;
                k_g[base + col] = acck[mt][nt][r];
                v_g[base + col] = accv[mt][nt][r];
            }
        }
}

// ---------------------------------------------------------------------------
// row-wise LN (128 threads per row, 2 waves)
__global__ void ln_kernel(const float* __restrict__ in, float* __restrict__ out,
                          const float* __restrict__ g, const float* __restrict__ bb) {
    int row = blockIdx.x, tid = threadIdx.x;
    float v = in[(long)row * DIM + tid];
    float s = v, ss = v * v;
    int lane = tid & 63, wv = tid >> 6;
    #pragma unroll
    for (int off = 32; off; off >>= 1) {
        s  += __shfl_xor(s, off, 64);
        ss += __shfl_xor(ss, off, 64);
    }
    __shared__ float red[4];
    if (lane == 0) { red[wv] = s; red[2 + wv] = ss; }
    __syncthreads();
    float S = red[0] + red[1], SS = red[2] + red[3];
    float mu = S * (1.0f / DIM);
    float var = fmaxf(SS * (1.0f / DIM) - mu * mu, 0.0f);
    float rstd = rsqrtf(var + EPS_LN);
    out[(long)row * DIM + tid] = (v - mu) * rstd * g[tid] + bb[tid];
}

// ---------------------------------------------------------------------------
// q = LN(x_out)@q_w ; 8 tokens / block of 256 (fp32)
__global__ void q_proj_kernel(const float* __restrict__ x_out,
                              const float* __restrict__ q_w,
                              const float* __restrict__ ln_g,
                              const float* __restrict__ ln_b,
                              float* __restrict__ q) {
    __shared__ float sx[8][DIM];
    __shared__ float sxln[8][DIM];
    int tid = threadIdx.x;
    long base = (long)blockIdx.x * 8;

    #pragma unroll
    for (int kk = 0; kk < 4; ++kk) {
        int idx = kk * 256 + tid;
        int r = idx >> 7, d = idx & 127;
        sx[r][d] = x_out[(base + r) * DIM + d];
    }
    __syncthreads();

    int wv = tid >> 6, lane = tid & 63;
    #pragma unroll
    for (int rr = 0; rr < 2; ++rr) {
        int r = wv * 2 + rr;
        float v0 = sx[r][lane], v1 = sx[r][lane + 64];
        float s = v0 + v1, ss = v0 * v0 + v1 * v1;
        #pragma unroll
        for (int off = 32; off; off >>= 1) {
            s  += __shfl_xor(s, off, 64);
            ss += __shfl_xor(ss, off, 64);
        }
        float mu = s * (1.0f / DIM);
        float var = fmaxf(ss * (1.0f / DIM) - mu * mu, 0.0f);
        float rstd = rsqrtf(var + EPS_LN);
        sxln[r][lane]      = (v0 - mu) * rstd * ln_g[lane]      + ln_b[lane];
        sxln[r][lane + 64] = (v1 - mu) * rstd * ln_g[lane + 64] + ln_b[lane + 64];
    }
    __syncthreads();

    int d = tid & 127, half = tid >> 7;
    float acc[4] = {0.f, 0.f, 0.f, 0.f};
    for (int i = 0; i < DIM; ++i) {
        float w = q_w[i * DIM + d];
        #pragma unroll
        for (int r = 0; r < 4; ++r) acc[r] += sxln[half * 4 + r][i] * w;
    }
    #pragma unroll
    for (int r = 0; r < 4; ++r)
        q[(base + half * 4 + r) * DIM + d] = acc[r];
}

// ---------------------------------------------------------------------------
__global__ void zero_kernel(float* __restrict__ p, int n) {
    int i = blockIdx.x * blockDim.x + threadIdx.x;
    if (i < n) p[i] = 0.0f;
}

// ---------------------------------------------------------------------------
__global__ void attn_kernel(const float* __restrict__ k_g,
                            const float* __restrict__ q,
                            const float* __restrict__ rpb,
                            const float* __restrict__ tau,
                            float* __restrict__ attn_out,
                            float* __restrict__ col_sums) {
    int tid = threadIdx.x;
    int wv = tid >> 6, lane = tid & 63;
    int cell = blockIdx.x * 4 + wv;
    int b = cell >> 14;
    int rem = cell & 16383;
    int g = rem >> 12;
    int pos = rem & 4095;
    int h = pos >> 6, w = pos & 63;

    const float2* kp = (const float2*)(k_g + (long)cell * DIM);
    float2 kv2 = kp[lane];
    float scale = expf(tau[0]);

    float l[9];
    #pragma unroll
    for (int t = 0; t < 9; ++t) {
        int n = nb_index(h, w, t);
        const float2* qp = (const float2*)(q + ((long)b * NPOS + n) * DIM);
        float2 qv = qp[lane];
        float p = kv2.x * qv.x + kv2.y * qv.y;
        #pragma unroll
        for (int off = 32; off; off >>= 1) p += __shfl_xor(p, off, 64);
        l[t] = (p + rpb[g * 9 + t]) * scale;
    }
    float m = l[0];
    #pragma unroll
    for (int t = 1; t < 9; ++t) m = fmaxf(m, l[t]);
    float e[9], s = 0.f;
    #pragma unroll
    for (int t = 0; t < 9; ++t) { e[t] = __expf(l[t] - m); s += e[t]; }
    float inv = 1.0f / s;

    float myv = 0.f; int myn = 0;
    #pragma unroll
    for (int t = 0; t < 9; ++t) {
        float a = e[t] * inv + EPS_A;
        if (lane == t) { myv = a; myn = nb_index(h, w, t); }
    }
    if (lane < 9) {
        attn_out[(long)cell * 9 + lane] = myv;
        atomicAdd(&col_sums[b * NPOS + myn], myv);
    }
}

// ---------------------------------------------------------------------------
__global__ void acol_upd_kernel(const float* __restrict__ attn_out,
                                const float* __restrict__ col_sums,
                                const float* __restrict__ v_g,
                                float* __restrict__ acol_out,
                                float* __restrict__ x_out) {
    __shared__ float sA[36];
    int tid = threadIdx.x;
    int row = blockIdx.x;               // b*NPOS+pos
    int b = row >> 12, pos = row & 4095;
    int h = pos >> 6, w = pos & 63;

    if (tid < 36) {
        int g = tid / 9, t = tid % 9;
        long ci = ((long)(b * 4 + g) * NPOS + pos) * 9 + t;
        float a = attn_out[ci];
        float cs = col_sums[b * NPOS + nb_index(h, w, t)];
        float A = a / (cs + 1e-8f);
        sA[tid] = A;
        acol_out[ci] = A;
    }
    __syncthreads();

    int nn[9];
    #pragma unroll
    for (int t = 0; t < 9; ++t) nn[t] = nb_index(h, w, t);

    float acc = 0.f;
    #pragma unroll
    for (int g = 0; g < 4; ++g) {
        const float* vb = v_g + (long)(b * 4 + g) * NPOS * DIM;
        #pragma unroll
        for (int t = 0; t < 9; ++t) {
            acc += sA[g * 9 + t] * vb[(long)nn[t] * DIM + tid];
        }
    }
    x_out[(long)row * DIM + tid] += acc;
}

// ---------------------------------------------------------------------------
__global__ void mlp_kernel(float* __restrict__ x_out,
                           const float* __restrict__ w1, const float* __restrict__ b1,
                           const float* __restrict__ w2, const float* __restrict__ b2,
                           const float* __restrict__ ln_g, const float* __restrict__ ln_b) {
    __shared__ float sx[4][DIM];
    __shared__ float sh[4][2 * DIM];
    __shared__ float sm[4][DIM];
    int tid = threadIdx.x;
    long base = (long)blockIdx.x * 4;

    #pragma unroll
    for (int kk = 0; kk < 2; ++kk) {
        int idx = kk * 256 + tid;
        int r = idx >> 7, d = idx & 127;
        sx[r][d] = x_out[(base + r) * DIM + d];
    }
    __syncthreads();

    int j = tid;
    float bj = b1[j];
    float acc[4] = {bj, bj, bj, bj};
    for (int i = 0; i < DIM; ++i) {
        float w = w1[i * 2 * DIM + j];
        #pragma unroll
        for (int r = 0; r < 4; ++r) acc[r] += sx[r][i] * w;
    }
    #pragma unroll
    for (int r = 0; r < 4; ++r) {
        float hv = acc[r];
        hv = 0.5f * hv * (1.0f + erff(hv * 0.70710678118654752f));
        sh[r][j] = hv;
    }
    __syncthreads();

    int d = tid & 127, half = tid >> 7;
    float o0 = b2[d], o1 = b2[d];
    for (int jj = 0; jj < 2 * DIM; ++jj) {
        float w = w2[jj * DIM + d];
        o0 += sh[half * 2 + 0][jj] * w;
        o1 += sh[half * 2 + 1][jj] * w;
    }
    sm[half * 2 + 0][d] = o0;
    sm[half * 2 + 1][d] = o1;
    __syncthreads();

    int wv = tid >> 6, lane = tid & 63;
    float v0 = sm[wv][lane], v1 = sm[wv][lane + 64];
    float s = v0 + v1, ss = v0 * v0 + v1 * v1;
    #pragma unroll
    for (int off = 32; off; off >>= 1) {
        s  += __shfl_xor(s, off, 64);
        ss += __shfl_xor(ss, off, 64);
    }
    float mu = s * (1.0f / DIM);
    float var = fmaxf(ss * (1.0f / DIM) - mu * mu, 0.0f);
    float rstd = rsqrtf(var + EPS_LN);
    x_out[(base + wv) * DIM + lane] =
        sx[wv][lane] + (v0 - mu) * rstd * ln_g[lane] + ln_b[lane];
    x_out[(base + wv) * DIM + lane + 64] =
        sx[wv][lane + 64] + (v1 - mu) * rstd * ln_g[lane + 64] + ln_b[lane + 64];
}

// ---------------------------------------------------------------------------
extern "C" void kernel_launch(void* const* d_in, const int* in_sizes, int n_in,
                              void* d_out, int out_size, void* d_ws, size_t ws_size,
                              hipStream_t stream) {
    const float* x        = (const float*)d_in[0];
    const float* conv_w   = (const float*)d_in[1];
    const float* q_w      = (const float*)d_in[2];
    const float* k_w      = (const float*)d_in[3];
    const float* v_w      = (const float*)d_in[4];
    const float* mlp_w1   = (const float*)d_in[5];
    const float* mlp_b1   = (const float*)d_in[6];
    const float* mlp_w2   = (const float*)d_in[7];
    const float* mlp_b2   = (const float*)d_in[8];
    const float* ln_in_g  = (const float*)d_in[9];
    const float* ln_in_b  = (const float*)d_in[10];
    const float* ln_out_g = (const float*)d_in[11];
    const float* ln_out_b = (const float*)d_in[12];
    const float* tau      = (const float*)d_in[13];
    const float* rpb      = (const float*)d_in[14];

    float* out_x    = (float*)d_out;                        // [4][4096][128]
    float* out_attn = out_x + (long)BN * NPOS * DIM;        // [4][4][4096][9]
    float* out_acol = out_attn + (long)BN * 4 * NPOS * 9;   // [4][4][4096][9]

    char* ws = (char*)d_ws;
    float* k_g = (float*)ws;            ws += (long)BN * 4 * NPOS * DIM * 4;   // 33.6 MB
    float* v_g = (float*)ws;            ws += (long)BN * 4 * NPOS * DIM * 4;   // 33.6 MB
    float* seed = (float*)ws;           ws += (long)BN * NPOS * DIM * 4;       // 8.4 MB
    unsigned short* x_bf = (unsigned short*)ws;                                // 16.8 MB
    float* qbuf = (float*)ws;           ws += (long)BN * NTOK * DIM * 2;       // qbuf aliases x_bf (used after prep phase)
    unsigned short* xln_bf = (unsigned short*)ws; ws += (long)BN * NTOK * DIM * 2;  // 16.8 MB
    unsigned short* wt_conv = (unsigned short*)ws; ws += 1152L * DIM * 2;      // 294 KB
    unsigned short* kwt = (unsigned short*)ws;     ws += (long)DIM * DIM * 2;
    unsigned short* vwt = (unsigned short*)ws;     ws += (long)DIM * DIM * 2;
    float* col_sums = (float*)ws;       ws += (long)BN * NPOS * 4;

    prep_ln_kernel<<<16384, 256, 0, stream>>>(x, ln_in_g, ln_in_b, x_bf, xln_bf);
    conv_wt_kernel<<<dim3(128, 9), 128, 0, stream>>>(conv_w, wt_conv);
    kv_wt_kernel<<<128, 128, 0, stream>>>(k_w, v_w, kwt, vwt);

    kv_mfma_kernel<<<1024, 256, 0, stream>>>(x_bf, xln_bf, kwt, vwt, k_g, v_g);
    conv_mfma_kernel<<<256, 256, 0, stream>>>(x_bf, wt_conv, seed);
    ln_kernel<<<BN * NPOS, 128, 0, stream>>>(seed, out_x, ln_out_g, ln_out_b);

    for (int it = 0; it < 3; ++it) {
        q_proj_kernel<<<2048, 256, 0, stream>>>(out_x, q_w, ln_out_g, ln_out_b, qbuf);
        zero_kernel<<<(BN * NPOS + 255) / 256, 256, 0, stream>>>(col_sums, BN * NPOS);
        attn_kernel<<<16384, 256, 0, stream>>>(k_g, qbuf, rpb, tau, out_attn, col_sums);
        acol_upd_kernel<<<16384, 128, 0, stream>>>(out_attn, col_sums, v_g, out_acol, out_x);
        mlp_kernel<<<4096, 256, 0, stream>>>(out_x, mlp_w1, mlp_b1, mlp_w2, mlp_b2,
                                             ln_out_g, ln_out_b);
    }
}

// Round 3
// 437.856 us; speedup vs baseline: 1.9008x; 1.3091x over previous
//
#include <hip/hip_runtime.h>
#include <hip/hip_bf16.h>
#include <math.h>

#define BN 4
#define HIq 128
#define WIq 128
#define DIM 128
#define HOq 64
#define WOq 64
#define NPOS 4096      // HO*WO
#define NTOK 16384     // HI*WI
#define EPS_LN 1e-5f
#define EPS_A 1e-6f

typedef __attribute__((ext_vector_type(8))) short bf16x8;
typedef __attribute__((ext_vector_type(4))) float f32x4;

__device__ __forceinline__ unsigned short f2bf(float f) {
    unsigned int u = __float_as_uint(f);
    u = (u + 0x7FFFu + ((u >> 16) & 1u)) >> 16;
    return (unsigned short)u;
}

__device__ __forceinline__ int nb_index(int h, int w, int t) {
    int ch = min(max(h, 1), HOq - 2);
    int cw = min(max(w, 1), WOq - 2);
    int dr = t / 3 - 1, dc = t % 3 - 1;
    return (ch + dr) * WOq + (cw + dc);
}

// ---------------------------------------------------------------------------
// x -> bf16, LN(x) -> bf16. Wave wv handles row blockIdx*4+wv.
__global__ void prep_ln_kernel(const float* __restrict__ x,
                               const float* __restrict__ g,
                               const float* __restrict__ bb,
                               unsigned short* __restrict__ x_bf,
                               unsigned short* __restrict__ xln_bf) {
    int tid = threadIdx.x, wv = tid >> 6, lane = tid & 63;
    long row = (long)blockIdx.x * 4 + wv;
    const float* xr = x + row * DIM;
    float v0 = xr[lane], v1 = xr[lane + 64];
    float s = v0 + v1, ss = v0 * v0 + v1 * v1;
    #pragma unroll
    for (int off = 32; off; off >>= 1) {
        s  += __shfl_xor(s, off, 64);
        ss += __shfl_xor(ss, off, 64);
    }
    float mu = s * (1.0f / DIM);
    float var = fmaxf(ss * (1.0f / DIM) - mu * mu, 0.0f);
    float rstd = rsqrtf(var + EPS_LN);
    x_bf[row * DIM + lane]        = f2bf(v0);
    x_bf[row * DIM + lane + 64]   = f2bf(v1);
    xln_bf[row * DIM + lane]      = f2bf((v0 - mu) * rstd * g[lane] + bb[lane]);
    xln_bf[row * DIM + lane + 64] = f2bf((v1 - mu) * rstd * g[lane + 64] + bb[lane + 64]);
}

// ---------------------------------------------------------------------------
// conv_w [O][I][3][3] -> wt [o][tap*128+i] bf16
__global__ void conv_wt_kernel(const float* __restrict__ cw, unsigned short* __restrict__ wt) {
    int o = blockIdx.x, tap = blockIdx.y, i = threadIdx.x;
    wt[(long)o * 1152 + tap * 128 + i] = f2bf(cw[((long)o * 128 + i) * 9 + tap]);
}

// k_w/v_w/q_w [i][o] -> [o][i] bf16 ; mlp_w1 [i][j](128x256) -> [j][i] ;
// mlp_w2 [j][o](256x128) -> [o][j]
__global__ void wt_all_kernel(const float* __restrict__ kw, const float* __restrict__ vw,
                              const float* __restrict__ qw,
                              const float* __restrict__ w1, const float* __restrict__ w2,
                              unsigned short* __restrict__ kwt, unsigned short* __restrict__ vwt,
                              unsigned short* __restrict__ qwt,
                              unsigned short* __restrict__ w1t, unsigned short* __restrict__ w2t) {
    int o = blockIdx.x, i = threadIdx.x;   // 128 x 128
    kwt[o * DIM + i] = f2bf(kw[i * DIM + o]);
    vwt[o * DIM + i] = f2bf(vw[i * DIM + o]);
    qwt[o * DIM + i] = f2bf(qw[i * DIM + o]);
    // w1: [i=128][j=256] -> w1t[j=256][i=128]
    w1t[(2 * o) * DIM + i]     = f2bf(w1[i * 256 + 2 * o]);
    w1t[(2 * o + 1) * DIM + i] = f2bf(w1[i * 256 + 2 * o + 1]);
    // w2: [j=256][o=128] -> w2t[o=128][j=256]
    w2t[o * 256 + i]       = f2bf(w2[i * DIM + o]);
    w2t[o * 256 + 128 + i] = f2bf(w2[(128 + i) * DIM + o]);
}

// ---------------------------------------------------------------------------
// Conv as implicit-im2col MFMA GEMM (unchanged from round 2).
__global__ __launch_bounds__(256) void conv_mfma_kernel(
        const unsigned short* __restrict__ x_bf,
        const unsigned short* __restrict__ wt,
        float* __restrict__ seed) {
    __shared__ unsigned short As[64][40];
    __shared__ unsigned short Bs[128][40];
    int tid = threadIdx.x;
    int wv = tid >> 6, lane = tid & 63;
    int quad = lane >> 4, l15 = lane & 15;
    int wr = wv >> 1, wc = wv & 1;
    int b = blockIdx.x >> 6, ho = blockIdx.x & 63;

    f32x4 acc[2][4];
    #pragma unroll
    for (int mt = 0; mt < 2; ++mt)
        #pragma unroll
        for (int nt = 0; nt < 4; ++nt) acc[mt][nt] = (f32x4){0.f, 0.f, 0.f, 0.f};

    int m = tid >> 2, seg = tid & 3;
    for (int tap = 0; tap < 9; ++tap) {
        int kh = tap / 3, kw = tap % 3;
        int hi = 2 * ho - 1 + kh;
        int wi = 2 * m - 1 + kw;
        bool ok = (hi >= 0) && (hi < HIq) && (wi >= 0) && (wi < WIq);
        long arow = (((long)b * HIq + hi) * WIq + wi) * DIM;
        #pragma unroll
        for (int ib = 0; ib < 4; ++ib) {
            __syncthreads();
            int4 av = {0, 0, 0, 0};
            if (ok) av = *(const int4*)(x_bf + arow + ib * 32 + seg * 8);
            *(int4*)&As[m][seg * 8] = av;
            #pragma unroll
            for (int r2 = 0; r2 < 2; ++r2) {
                int lin = r2 * 256 + tid;
                int n = lin >> 2, sg = lin & 3;
                *(int4*)&Bs[n][sg * 8] =
                    *(const int4*)(wt + (long)n * 1152 + tap * 128 + ib * 32 + sg * 8);
            }
            __syncthreads();
            bf16x8 afr[2], bfr[4];
            #pragma unroll
            for (int mt = 0; mt < 2; ++mt)
                afr[mt] = *(bf16x8*)&As[wr * 32 + mt * 16 + l15][quad * 8];
            #pragma unroll
            for (int nt = 0; nt < 4; ++nt)
                bfr[nt] = *(bf16x8*)&Bs[wc * 64 + nt * 16 + l15][quad * 8];
            #pragma unroll
            for (int mt = 0; mt < 2; ++mt)
                #pragma unroll
                for (int nt = 0; nt < 4; ++nt)
                    acc[mt][nt] = __builtin_amdgcn_mfma_f32_16x16x32_bf16(
                        afr[mt], bfr[nt], acc[mt][nt], 0, 0, 0);
        }
    }
    long outb = ((long)b * NPOS + ho * WOq) * DIM;
    #pragma unroll
    for (int mt = 0; mt < 2; ++mt)
        #pragma unroll
        for (int r = 0; r < 4; ++r) {
            int wo = wr * 32 + mt * 16 + quad * 4 + r;
            #pragma unroll
            for (int nt = 0; nt < 4; ++nt) {
                int col = wc * 64 + nt * 16 + l15;
                seed[outb + (long)wo * DIM + col] = acc[mt][nt][r];
            }
        }
}

// ---------------------------------------------------------------------------
// kv dual MFMA GEMM (unchanged from round 2).
__global__ __launch_bounds__(256) void kv_mfma_kernel(
        const unsigned short* __restrict__ x_bf,
        const unsigned short* __restrict__ xln_bf,
        const unsigned short* __restrict__ kwt,
        const unsigned short* __restrict__ vwt,
        float* __restrict__ k_g, float* __restrict__ v_g) {
    __shared__ unsigned short Ak[64][40], Av[64][40];
    __shared__ unsigned short Bk[128][40], Bv[128][40];
    int tid = threadIdx.x;
    int wv = tid >> 6, lane = tid & 63;
    int quad = lane >> 4, l15 = lane & 15;
    int wr = wv >> 1, wc = wv & 1;
    long tokBase = (long)blockIdx.x * 64;

    f32x4 acck[2][4], accv[2][4];
    #pragma unroll
    for (int mt = 0; mt < 2; ++mt)
        #pragma unroll
        for (int nt = 0; nt < 4; ++nt) {
            acck[mt][nt] = (f32x4){0.f, 0.f, 0.f, 0.f};
            accv[mt][nt] = (f32x4){0.f, 0.f, 0.f, 0.f};
        }

    int m = tid >> 2, seg = tid & 3;
    #pragma unroll
    for (int ib = 0; ib < 4; ++ib) {
        __syncthreads();
        *(int4*)&Ak[m][seg * 8] = *(const int4*)(xln_bf + (tokBase + m) * DIM + ib * 32 + seg * 8);
        *(int4*)&Av[m][seg * 8] = *(const int4*)(x_bf   + (tokBase + m) * DIM + ib * 32 + seg * 8);
        #pragma unroll
        for (int r2 = 0; r2 < 2; ++r2) {
            int lin = r2 * 256 + tid;
            int n = lin >> 2, sg = lin & 3;
            *(int4*)&Bk[n][sg * 8] = *(const int4*)(kwt + (long)n * DIM + ib * 32 + sg * 8);
            *(int4*)&Bv[n][sg * 8] = *(const int4*)(vwt + (long)n * DIM + ib * 32 + sg * 8);
        }
        __syncthreads();
        bf16x8 ak[2], av2[2], bk[4], bv[4];
        #pragma unroll
        for (int mt = 0; mt < 2; ++mt) {
            ak[mt]  = *(bf16x8*)&Ak[wr * 32 + mt * 16 + l15][quad * 8];
            av2[mt] = *(bf16x8*)&Av[wr * 32 + mt * 16 + l15][quad * 8];
        }
        #pragma unroll
        for (int nt = 0; nt < 4; ++nt) {
            bk[nt] = *(bf16x8*)&Bk[wc * 64 + nt * 16 + l15][quad * 8];
            bv[nt] = *(bf16x8*)&Bv[wc * 64 + nt * 16 + l15][quad * 8];
        }
        #pragma unroll
        for (int mt = 0; mt < 2; ++mt)
            #pragma unroll
            for (int nt = 0; nt < 4; ++nt) {
                acck[mt][nt] = __builtin_amdgcn_mfma_f32_16x16x32_bf16(ak[mt],  bk[nt], acck[mt][nt], 0, 0, 0);
                accv[mt][nt] = __builtin_amdgcn_mfma_f32_16x16x32_bf16(av2[mt], bv[nt], accv[mt][nt], 0, 0, 0);
            }
    }
    #pragma unroll
    for (int mt = 0; mt < 2; ++mt)
        #pragma unroll
        for (int r = 0; r < 4; ++r) {
            long tok = tokBase + wr * 32 + mt * 16 + quad * 4 + r;
            int b = (int)(tok >> 14);
            int pix = (int)(tok & 16383);
            int ih = pix >> 7, iw = pix & 127;
            int g = (ih & 1) * 2 + (iw & 1);
            int pos = (ih >> 1) * WOq + (iw >> 1);
            long base = ((long)(b * 4 + g) * NPOS + pos) * DIM;
            #pragma unroll
            for (int nt = 0; nt < 4; ++nt) {
                int col = wc * 64 + nt * 16 + l15;
                k_g[base + col] = acck[mt][nt][r];
                v_g[base + col] = accv[mt][nt][r];
            }
        }
}

// ---------------------------------------------------------------------------
__global__ void ln_kernel(const float* __restrict__ in, float* __restrict__ out,
                          const float* __restrict__ g, const float* __restrict__ bb) {
    int row = blockIdx.x, tid = threadIdx.x;
    float v = in[(long)row * DIM + tid];
    float s = v, ss = v * v;
    int lane = tid & 63, wv = tid >> 6;
    #pragma unroll
    for (int off = 32; off; off >>= 1) {
        s  += __shfl_xor(s, off, 64);
        ss += __shfl_xor(ss, off, 64);
    }
    __shared__ float red[4];
    if (lane == 0) { red[wv] = s; red[2 + wv] = ss; }
    __syncthreads();
    float S = red[0] + red[1], SS = red[2] + red[3];
    float mu = S * (1.0f / DIM);
    float var = fmaxf(SS * (1.0f / DIM) - mu * mu, 0.0f);
    float rstd = rsqrtf(var + EPS_LN);
    out[(long)row * DIM + tid] = (v - mu) * rstd * g[tid] + bb[tid];
}

// ---------------------------------------------------------------------------
// q = LN(x_out)@q_w via MFMA. Block = 64 tokens, 4 waves.
__global__ __launch_bounds__(256) void q_mfma_kernel(
        const float* __restrict__ x_out,
        const unsigned short* __restrict__ qwt,
        const float* __restrict__ ln_g, const float* __restrict__ ln_b,
        float* __restrict__ q) {
    __shared__ unsigned short sxbf[64][136];
    int tid = threadIdx.x;
    long base = (long)blockIdx.x * 64;

    // stage: LN(x_out) -> bf16. 4 threads per row; thread covers 32 cols.
    {
        int r = tid >> 2, qq = tid & 3;
        const float* xr = x_out + (base + r) * DIM + qq * 32;
        float vv[32];
        float s = 0.f, ss = 0.f;
        #pragma unroll
        for (int j = 0; j < 8; ++j) {
            float4 v4 = *(const float4*)(xr + j * 4);
            vv[j * 4 + 0] = v4.x; vv[j * 4 + 1] = v4.y;
            vv[j * 4 + 2] = v4.z; vv[j * 4 + 3] = v4.w;
            s += v4.x + v4.y + v4.z + v4.w;
            ss += v4.x * v4.x + v4.y * v4.y + v4.z * v4.z + v4.w * v4.w;
        }
        s  += __shfl_xor(s, 1, 64);  ss += __shfl_xor(ss, 1, 64);
        s  += __shfl_xor(s, 2, 64);  ss += __shfl_xor(ss, 2, 64);
        float mu = s * (1.0f / DIM);
        float var = fmaxf(ss * (1.0f / DIM) - mu * mu, 0.0f);
        float rstd = rsqrtf(var + EPS_LN);
        #pragma unroll
        for (int j = 0; j < 32; ++j) {
            int c = qq * 32 + j;
            sxbf[r][c] = f2bf((vv[j] - mu) * rstd * ln_g[c] + ln_b[c]);
        }
    }
    __syncthreads();

    int wv = tid >> 6, lane = tid & 63;
    int quad = lane >> 4, l15 = lane & 15;
    f32x4 acc[4][2];
    #pragma unroll
    for (int mt = 0; mt < 4; ++mt)
        #pragma unroll
        for (int nt = 0; nt < 2; ++nt) acc[mt][nt] = (f32x4){0.f, 0.f, 0.f, 0.f};

    #pragma unroll
    for (int kb = 0; kb < 4; ++kb) {
        bf16x8 afr[4], bfr[2];
        #pragma unroll
        for (int mt = 0; mt < 4; ++mt)
            afr[mt] = *(bf16x8*)&sxbf[mt * 16 + l15][kb * 32 + quad * 8];
        #pragma unroll
        for (int nt = 0; nt < 2; ++nt) {
            int n = wv * 32 + nt * 16 + l15;
            bfr[nt] = *(const bf16x8*)(qwt + (long)n * DIM + kb * 32 + quad * 8);
        }
        #pragma unroll
        for (int mt = 0; mt < 4; ++mt)
            #pragma unroll
            for (int nt = 0; nt < 2; ++nt)
                acc[mt][nt] = __builtin_amdgcn_mfma_f32_16x16x32_bf16(
                    afr[mt], bfr[nt], acc[mt][nt], 0, 0, 0);
    }
    #pragma unroll
    for (int mt = 0; mt < 4; ++mt)
        #pragma unroll
        for (int r = 0; r < 4; ++r) {
            long tok = base + mt * 16 + quad * 4 + r;
            #pragma unroll
            for (int nt = 0; nt < 2; ++nt) {
                int col = wv * 32 + nt * 16 + l15;
                q[tok * DIM + col] = acc[mt][nt][r];
            }
        }
}

// ---------------------------------------------------------------------------
__global__ void zero_kernel(float* __restrict__ p, int n) {
    int i = blockIdx.x * blockDim.x + threadIdx.x;
    if (i < n) p[i] = 0.0f;
}

// ---------------------------------------------------------------------------
__global__ void attn_kernel(const float* __restrict__ k_g,
                            const float* __restrict__ q,
                            const float* __restrict__ rpb,
                            const float* __restrict__ tau,
                            float* __restrict__ attn_out,
                            float* __restrict__ col_sums) {
    int tid = threadIdx.x;
    int wv = tid >> 6, lane = tid & 63;
    int cell = blockIdx.x * 4 + wv;
    int b = cell >> 14;
    int rem = cell & 16383;
    int g = rem >> 12;
    int pos = rem & 4095;
    int h = pos >> 6, w = pos & 63;

    const float2* kp = (const float2*)(k_g + (long)cell * DIM);
    float2 kv2 = kp[lane];
    float scale = expf(tau[0]);

    float l[9];
    #pragma unroll
    for (int t = 0; t < 9; ++t) {
        int n = nb_index(h, w, t);
        const float2* qp = (const float2*)(q + ((long)b * NPOS + n) * DIM);
        float2 qv = qp[lane];
        float p = kv2.x * qv.x + kv2.y * qv.y;
        #pragma unroll
        for (int off = 32; off; off >>= 1) p += __shfl_xor(p, off, 64);
        l[t] = (p + rpb[g * 9 + t]) * scale;
    }
    float m = l[0];
    #pragma unroll
    for (int t = 1; t < 9; ++t) m = fmaxf(m, l[t]);
    float e[9], s = 0.f;
    #pragma unroll
    for (int t = 0; t < 9; ++t) { e[t] = __expf(l[t] - m); s += e[t]; }
    float inv = 1.0f / s;

    float myv = 0.f; int myn = 0;
    #pragma unroll
    for (int t = 0; t < 9; ++t) {
        float a = e[t] * inv + EPS_A;
        if (lane == t) { myv = a; myn = nb_index(h, w, t); }
    }
    if (lane < 9) {
        attn_out[(long)cell * 9 + lane] = myv;
        atomicAdd(&col_sums[b * NPOS + myn], myv);
    }
}

// ---------------------------------------------------------------------------
__global__ void acol_upd_kernel(const float* __restrict__ attn_out,
                                const float* __restrict__ col_sums,
                                const float* __restrict__ v_g,
                                float* __restrict__ acol_out,
                                float* __restrict__ x_out) {
    __shared__ float sA[36];
    int tid = threadIdx.x;
    int row = blockIdx.x;
    int b = row >> 12, pos = row & 4095;
    int h = pos >> 6, w = pos & 63;

    if (tid < 36) {
        int g = tid / 9, t = tid % 9;
        long ci = ((long)(b * 4 + g) * NPOS + pos) * 9 + t;
        float a = attn_out[ci];
        float cs = col_sums[b * NPOS + nb_index(h, w, t)];
        float A = a / (cs + 1e-8f);
        sA[tid] = A;
        acol_out[ci] = A;
    }
    __syncthreads();

    int nn[9];
    #pragma unroll
    for (int t = 0; t < 9; ++t) nn[t] = nb_index(h, w, t);

    float acc = 0.f;
    #pragma unroll
    for (int g = 0; g < 4; ++g) {
        const float* vb = v_g + (long)(b * 4 + g) * NPOS * DIM;
        #pragma unroll
        for (int t = 0; t < 9; ++t) {
            acc += sA[g * 9 + t] * vb[(long)nn[t] * DIM + tid];
        }
    }
    x_out[(long)row * DIM + tid] += acc;
}

// ---------------------------------------------------------------------------
// Fused MFMA MLP: h=gelu(x@w1+b1); o=h@w2+b2; x += LN(o). 64 tokens/block.
__global__ __launch_bounds__(256) void mlp_mfma_kernel(
        float* __restrict__ x_out,
        const unsigned short* __restrict__ w1t,  // [256][128]
        const unsigned short* __restrict__ w2t,  // [128][256]
        const float* __restrict__ b1, const float* __restrict__ b2,
        const float* __restrict__ ln_g, const float* __restrict__ ln_b) {
    __shared__ __align__(16) char smem[51200];
    unsigned short (*sxbf)[136] = (unsigned short(*)[136])smem;          // 17408 B
    unsigned short (*h_s)[264]  = (unsigned short(*)[264])(smem + 17408); // 33792 B
    float (*o_s)[132]           = (float(*)[132])smem;                    // aliased

    int tid = threadIdx.x;
    long base = (long)blockIdx.x * 64;
    int wv = tid >> 6, lane = tid & 63;
    int quad = lane >> 4, l15 = lane & 15;

    // stage x -> bf16
    {
        int r = tid >> 2, seg = tid & 3;
        const float* xr = x_out + (base + r) * DIM + seg * 32;
        #pragma unroll
        for (int j = 0; j < 4; ++j) {
            float4 a = *(const float4*)(xr + j * 8);
            float4 c = *(const float4*)(xr + j * 8 + 4);
            unsigned short u[8] = {f2bf(a.x), f2bf(a.y), f2bf(a.z), f2bf(a.w),
                                   f2bf(c.x), f2bf(c.y), f2bf(c.z), f2bf(c.w)};
            *(int4*)&sxbf[r][seg * 32 + j * 8] = *(int4*)u;
        }
    }
    __syncthreads();

    // GEMM1: M=64, N=256 (wave wv -> cols wv*64..+64), K=128
    f32x4 acc1[4][4];
    #pragma unroll
    for (int mt = 0; mt < 4; ++mt)
        #pragma unroll
        for (int nt = 0; nt < 4; ++nt) acc1[mt][nt] = (f32x4){0.f, 0.f, 0.f, 0.f};
    #pragma unroll
    for (int kb = 0; kb < 4; ++kb) {
        bf16x8 afr[4], bfr[4];
        #pragma unroll
        for (int mt = 0; mt < 4; ++mt)
            afr[mt] = *(bf16x8*)&sxbf[mt * 16 + l15][kb * 32 + quad * 8];
        #pragma unroll
        for (int nt = 0; nt < 4; ++nt) {
            int n = wv * 64 + nt * 16 + l15;
            bfr[nt] = *(const bf16x8*)(w1t + (long)n * DIM + kb * 32 + quad * 8);
        }
        #pragma unroll
        for (int mt = 0; mt < 4; ++mt)
            #pragma unroll
            for (int nt = 0; nt < 4; ++nt)
                acc1[mt][nt] = __builtin_amdgcn_mfma_f32_16x16x32_bf16(
                    afr[mt], bfr[nt], acc1[mt][nt], 0, 0, 0);
    }
    // bias + gelu -> h_s (bf16)
    #pragma unroll
    for (int nt = 0; nt < 4; ++nt) {
        int col = wv * 64 + nt * 16 + l15;
        float bj = b1[col];
        #pragma unroll
        for (int mt = 0; mt < 4; ++mt)
            #pragma unroll
            for (int r = 0; r < 4; ++r) {
                int row = mt * 16 + quad * 4 + r;
                float hv = acc1[mt][nt][r] + bj;
                hv = 0.5f * hv * (1.0f + erff(hv * 0.70710678118654752f));
                h_s[row][col] = f2bf(hv);
            }
    }
    __syncthreads();

    // GEMM2: M=64, N=128 (wave wv -> cols wv*32..+32), K=256
    f32x4 acc2[4][2];
    #pragma unroll
    for (int mt = 0; mt < 4; ++mt)
        #pragma unroll
        for (int nt = 0; nt < 2; ++nt) acc2[mt][nt] = (f32x4){0.f, 0.f, 0.f, 0.f};
    #pragma unroll
    for (int kb = 0; kb < 8; ++kb) {
        bf16x8 afr[4], bfr[2];
        #pragma unroll
        for (int mt = 0; mt < 4; ++mt)
            afr[mt] = *(bf16x8*)&h_s[mt * 16 + l15][kb * 32 + quad * 8];
        #pragma unroll
        for (int nt = 0; nt < 2; ++nt) {
            int n = wv * 32 + nt * 16 + l15;
            bfr[nt] = *(const bf16x8*)(w2t + (long)n * 256 + kb * 32 + quad * 8);
        }
        #pragma unroll
        for (int mt = 0; mt < 4; ++mt)
            #pragma unroll
            for (int nt = 0; nt < 2; ++nt)
                acc2[mt][nt] = __builtin_amdgcn_mfma_f32_16x16x32_bf16(
                    afr[mt], bfr[nt], acc2[mt][nt], 0, 0, 0);
    }
    __syncthreads();   // h_s dead; safe to write aliased o_s

    #pragma unroll
    for (int nt = 0; nt < 2; ++nt) {
        int col = wv * 32 + nt * 16 + l15;
        float bj = b2[col];
        #pragma unroll
        for (int mt = 0; mt < 4; ++mt)
            #pragma unroll
            for (int r = 0; r < 4; ++r)
                o_s[mt * 16 + quad * 4 + r][col] = acc2[mt][nt][r] + bj;
    }
    __syncthreads();

    // LN(o) + residual. 4 threads per row, 32 cols each.
    {
        int r = tid >> 2, qq = tid & 3;
        float s = 0.f, ss = 0.f;
        #pragma unroll
        for (int j = 0; j < 32; ++j) {
            float v = o_s[r][qq * 32 + j];
            s += v; ss += v * v;
        }
        s  += __shfl_xor(s, 1, 64);  ss += __shfl_xor(ss, 1, 64);
        s  += __shfl_xor(s, 2, 64);  ss += __shfl_xor(ss, 2, 64);
        float mu = s * (1.0f / DIM);
        float var = fmaxf(ss * (1.0f / DIM) - mu * mu, 0.0f);
        float rstd = rsqrtf(var + EPS_LN);
        float* xr = x_out + (base + r) * DIM + qq * 32;
        #pragma unroll
        for (int j = 0; j < 32; ++j) {
            int c = qq * 32 + j;
            xr[j] = xr[j] + (o_s[r][c] - mu) * rstd * ln_g[c] + ln_b[c];
        }
    }
}

// ---------------------------------------------------------------------------
extern "C" void kernel_launch(void* const* d_in, const int* in_sizes, int n_in,
                              void* d_out, int out_size, void* d_ws, size_t ws_size,
                              hipStream_t stream) {
    const float* x        = (const float*)d_in[0];
    const float* conv_w   = (const float*)d_in[1];
    const float* q_w      = (const float*)d_in[2];
    const float* k_w      = (const float*)d_in[3];
    const float* v_w      = (const float*)d_in[4];
    const float* mlp_w1   = (const float*)d_in[5];
    const float* mlp_b1   = (const float*)d_in[6];
    const float* mlp_w2   = (const float*)d_in[7];
    const float* mlp_b2   = (const float*)d_in[8];
    const float* ln_in_g  = (const float*)d_in[9];
    const float* ln_in_b  = (const float*)d_in[10];
    const float* ln_out_g = (const float*)d_in[11];
    const float* ln_out_b = (const float*)d_in[12];
    const float* tau      = (const float*)d_in[13];
    const float* rpb      = (const float*)d_in[14];

    float* out_x    = (float*)d_out;
    float* out_attn = out_x + (long)BN * NPOS * DIM;
    float* out_acol = out_attn + (long)BN * 4 * NPOS * 9;

    char* ws = (char*)d_ws;
    float* k_g = (float*)ws;            ws += (long)BN * 4 * NPOS * DIM * 4;
    float* v_g = (float*)ws;            ws += (long)BN * 4 * NPOS * DIM * 4;
    float* seed = (float*)ws;           ws += (long)BN * NPOS * DIM * 4;
    unsigned short* x_bf = (unsigned short*)ws;
    float* qbuf = (float*)ws;           ws += (long)BN * NTOK * DIM * 2;   // qbuf aliases x_bf
    unsigned short* xln_bf = (unsigned short*)ws; ws += (long)BN * NTOK * DIM * 2;
    unsigned short* wt_conv = (unsigned short*)ws; ws += 1152L * DIM * 2;
    unsigned short* kwt = (unsigned short*)ws;     ws += (long)DIM * DIM * 2;
    unsigned short* vwt = (unsigned short*)ws;     ws += (long)DIM * DIM * 2;
    unsigned short* qwt = (unsigned short*)ws;     ws += (long)DIM * DIM * 2;
    unsigned short* w1t = (unsigned short*)ws;     ws += 256L * DIM * 2;
    unsigned short* w2t = (unsigned short*)ws;     ws += 256L * DIM * 2;
    float* col_sums = (float*)ws;       ws += (long)BN * NPOS * 4;

    prep_ln_kernel<<<16384, 256, 0, stream>>>(x, ln_in_g, ln_in_b, x_bf, xln_bf);
    conv_wt_kernel<<<dim3(128, 9), 128, 0, stream>>>(conv_w, wt_conv);
    wt_all_kernel<<<128, 128, 0, stream>>>(k_w, v_w, q_w, mlp_w1, mlp_w2,
                                           kwt, vwt, qwt, w1t, w2t);

    kv_mfma_kernel<<<1024, 256, 0, stream>>>(x_bf, xln_bf, kwt, vwt, k_g, v_g);
    conv_mfma_kernel<<<256, 256, 0, stream>>>(x_bf, wt_conv, seed);
    ln_kernel<<<BN * NPOS, 128, 0, stream>>>(seed, out_x, ln_out_g, ln_out_b);

    for (int it = 0; it < 3; ++it) {
        q_mfma_kernel<<<256, 256, 0, stream>>>(out_x, qwt, ln_out_g, ln_out_b, qbuf);
        zero_kernel<<<(BN * NPOS + 255) / 256, 256, 0, stream>>>(col_sums, BN * NPOS);
        attn_kernel<<<16384, 256, 0, stream>>>(k_g, qbuf, rpb, tau, out_attn, col_sums);
        acol_upd_kernel<<<16384, 128, 0, stream>>>(out_attn, col_sums, v_g, out_acol, out_x);
        mlp_mfma_kernel<<<256, 256, 0, stream>>>(out_x, w1t, w2t, mlp_b1, mlp_b2,
                                                 ln_out_g, ln_out_b);
    }
}